// Round 8
// baseline (108.692 us; speedup 1.0000x reference)
//
#include <hip/hip_runtime.h>
#include <hip/hip_bf16.h>
#include <math.h>

#define BB    2
#define NN    20000
#define FF    128
#define EE    640000
#define EP    (EE + NN)      // edges + self loops = 660000
#define CAP   128            // bucket capacity per node (Poisson(33): P(>=128)~1e-43)
#define SLOPE 0.2f
#define GEMM_BLOCKS 625      // 40000 rows / 64
#define SCAT_BLOCKS ((EP + 255) / 256)

typedef __attribute__((ext_vector_type(8))) short bf16x8;
typedef __attribute__((ext_vector_type(4))) float f32x4;

static __device__ __forceinline__ ushort f2bf(float f) {
    unsigned u = __float_as_uint(f);
    u += 0x7fffu + ((u >> 16) & 1u);     // round-to-nearest-even
    return (ushort)(u >> 16);
}
static __device__ __forceinline__ float bflo(unsigned q) {
    return __uint_as_float(q << 16);
}
static __device__ __forceinline__ float bfhi(unsigned q) {
    return __uint_as_float(q & 0xffff0000u);
}

// ---------------------------------------------------------------------------
// Fused kernel. Blocks [0,625): MFMA GEMM h = bf16(x)@bf16(W)^T + a_src/a_dst.
// Blocks [625, 625+2579): edge scatter into fixed-capacity buckets.
// The two ranges share no data (cnt pre-zeroed by memset) -> scatter's
// atomic/random-write latency hides under the GEMM blocks' MFMA work.
// h stored batch-interleaved: uint[n*128 + pair*2 + b] = bf16x2(h[b][n][2p..])
// ---------------------------------------------------------------------------
__global__ __launch_bounds__(256) void fused_kernel(
    const float* __restrict__ x, const float* __restrict__ W,
    const float* __restrict__ att_src, const float* __restrict__ att_dst,
    const int* __restrict__ ei,
    unsigned* __restrict__ hbu, float* __restrict__ as2, float* __restrict__ ad2,
    int* __restrict__ cnt, ushort* __restrict__ buck)
{
    __shared__ ushort XL[64 * 128];    // 16 KB swizzled bf16 x-tile
    __shared__ ushort WL[128 * 128];   // 32 KB swizzled bf16 W (row c, col k)
    const int tid = threadIdx.x;

    if (blockIdx.x >= GEMM_BLOCKS) {
        // ---------------- scatter part ----------------
        int e = (blockIdx.x - GEMM_BLOCKS) * 256 + tid;
        if (e < EP) {
            int s, d;
            if (e < EE) {
                s = ei[e]; d = ei[EE + e];
                if ((unsigned)s < NN && (unsigned)d < NN) {
                    int slot = atomicAdd(&cnt[d], 1);
                    if (slot < CAP) buck[d * CAP + slot] = (ushort)s;
                }
            } else {
                s = d = e - EE;
                int slot = atomicAdd(&cnt[d], 1);
                if (slot < CAP) buck[d * CAP + slot] = (ushort)s;
            }
        }
        return;
    }

    // ---------------- GEMM part ----------------
    const int r0 = blockIdx.x * 64;

    // stage x tile: 64 rows x 128 f32 = 2048 float4
    {
        const float4* xg = (const float4*)(x + (size_t)r0 * 128);
        #pragma unroll
        for (int i = 0; i < 8; ++i) {
            int idx = tid + i * 256;          // float4 idx; 32 per row
            int r = idx >> 5, k = (idx & 31) * 4;
            float4 v = xg[idx];
            ushort4 p = { f2bf(v.x), f2bf(v.y), f2bf(v.z), f2bf(v.w) };
            unsigned byte = ((unsigned)r << 8) + ((unsigned)k << 1);
            byte ^= (unsigned)(r & 7) << 4;
            *(ushort4*)((char*)XL + byte) = p;
        }
    }
    // stage W: 128x128 f32 = 4096 float4
    {
        const float4* wg = (const float4*)W;
        #pragma unroll
        for (int i = 0; i < 16; ++i) {
            int idx = tid + i * 256;
            int c = idx >> 5, k = (idx & 31) * 4;
            float4 v = wg[idx];
            ushort4 p = { f2bf(v.x), f2bf(v.y), f2bf(v.z), f2bf(v.w) };
            unsigned byte = ((unsigned)c << 8) + ((unsigned)k << 1);
            byte ^= (unsigned)(c & 7) << 4;
            *(ushort4*)((char*)WL + byte) = p;
        }
    }
    __syncthreads();

    const int wid = tid >> 6, lane = tid & 63;
    const int l15 = lane & 15, lg = lane >> 4;
    f32x4 acc[8];
    #pragma unroll
    for (int i = 0; i < 8; ++i) acc[i] = (f32x4){0.f, 0.f, 0.f, 0.f};

    const int arow = wid * 16 + l15;
    #pragma unroll
    for (int kt = 0; kt < 4; ++kt) {
        unsigned abyte = ((unsigned)arow << 8) + (unsigned)(kt * 64 + lg * 16);
        abyte ^= (unsigned)(arow & 7) << 4;
        bf16x8 af = *(const bf16x8*)((const char*)XL + abyte);
        #pragma unroll
        for (int ct = 0; ct < 8; ++ct) {
            int c = ct * 16 + l15;
            unsigned bbyte = ((unsigned)c << 8) + (unsigned)(kt * 64 + lg * 16);
            bbyte ^= (unsigned)(c & 7) << 4;
            bf16x8 bfr = *(const bf16x8*)((const char*)WL + bbyte);
            acc[ct] = __builtin_amdgcn_mfma_f32_16x16x32_bf16(af, bfr, acc[ct], 0, 0, 0);
        }
    }

    // a_src/a_dst from f32 accumulators: row = wid*16 + lg*4 + reg, col = ct*16+l15
    float ps0=0,ps1=0,ps2=0,ps3=0, pd0=0,pd1=0,pd2=0,pd3=0;
    #pragma unroll
    for (int ct = 0; ct < 8; ++ct) {
        int c = ct * 16 + l15;
        float as_ = att_src[c], ad_ = att_dst[c];
        ps0 += acc[ct][0]*as_; pd0 += acc[ct][0]*ad_;
        ps1 += acc[ct][1]*as_; pd1 += acc[ct][1]*ad_;
        ps2 += acc[ct][2]*as_; pd2 += acc[ct][2]*ad_;
        ps3 += acc[ct][3]*as_; pd3 += acc[ct][3]*ad_;
    }
    #pragma unroll
    for (int o = 1; o < 16; o <<= 1) {
        ps0 += __shfl_xor(ps0, o, 64); pd0 += __shfl_xor(pd0, o, 64);
        ps1 += __shfl_xor(ps1, o, 64); pd1 += __shfl_xor(pd1, o, 64);
        ps2 += __shfl_xor(ps2, o, 64); pd2 += __shfl_xor(pd2, o, 64);
        ps3 += __shfl_xor(ps3, o, 64); pd3 += __shfl_xor(pd3, o, 64);
    }
    if (l15 == 0) {
        int rb = r0 + wid * 16 + lg * 4;     // multiple of 4; quads never cross NN
        #pragma unroll
        for (int q = 0; q < 4; ++q) {
            int r = rb + q;
            int b = (r >= NN);
            int n = r - b * NN;
            float ps = q==0?ps0 : q==1?ps1 : q==2?ps2 : ps3;
            float pd = q==0?pd0 : q==1?pd1 : q==2?pd2 : pd3;
            as2[n * 2 + b] = ps;             // batch-packed float2 halves
            ad2[n * 2 + b] = pd;
        }
    }

    // h epilogue: acc -> LDS bf16 (linear) -> batch-interleaved global write
    __syncthreads();
    ushort* hl = (ushort*)WL;          // reuse 16 KB of WL
    {
        int rb = wid * 16 + lg * 4;
        #pragma unroll
        for (int ct = 0; ct < 8; ++ct) {
            int c = ct * 16 + l15;
            hl[(rb+0) * 128 + c] = f2bf(acc[ct][0]);
            hl[(rb+1) * 128 + c] = f2bf(acc[ct][1]);
            hl[(rb+2) * 128 + c] = f2bf(acc[ct][2]);
            hl[(rb+3) * 128 + c] = f2bf(acc[ct][3]);
        }
    }
    __syncthreads();
    {
        const unsigned* hs = (const unsigned*)hl;   // 64 rows x 64 pairs
        #pragma unroll
        for (int i = 0; i < 16; ++i) {
            int idx = tid + i * 256;       // 0..4095
            int row = idx >> 6, p = idx & 63;
            int r = r0 + row;
            int b = (r >= NN);
            int n = r - b * NN;
            hbu[(size_t)n * 128 + p * 2 + b] = hs[row * 64 + p];
        }
    }
}

// ---------------------------------------------------------------------------
// Gather: 256 threads (4 waves) per node, both batches fused.
// One uint2 load per edge per lane (batch-interleaved h), unroll x2.
// ---------------------------------------------------------------------------
__global__ __launch_bounds__(256) void gather_kernel(
    const uint2* __restrict__ h,             // [N][64] uint2 {b0 pair, b1 pair}
    const int* __restrict__ cnt, const ushort* __restrict__ buck,
    const float2* __restrict__ as2, const float2* __restrict__ ad2,
    const float* __restrict__ bias, float* __restrict__ out)
{
    const int n = blockIdx.x;
    const int t = threadIdx.x;
    const int w = t >> 6, lane = t & 63;
    const int cn = min(cnt[n], CAP);

    __shared__ ushort ssrc[CAP];
    __shared__ float sw0[CAP], sw1[CAP];
    __shared__ float4 part[192];
    __shared__ float dsum[8];

    const float2 ad = ad2[n];
    float den0 = 0.f, den1 = 0.f;
    if (t < cn) {
        int s = buck[n * CAP + t];
        float2 as = as2[s];
        float l0 = as.x + ad.x; l0 = l0 > 0.f ? l0 : SLOPE * l0;
        float l1 = as.y + ad.y; l1 = l1 > 0.f ? l1 : SLOPE * l1;
        float w0 = __expf(l0), w1 = __expf(l1);
        ssrc[t] = (ushort)s; sw0[t] = w0; sw1[t] = w1;
        den0 = w0; den1 = w1;
    }
    #pragma unroll
    for (int o = 32; o > 0; o >>= 1) {
        den0 += __shfl_xor(den0, o, 64);
        den1 += __shfl_xor(den1, o, 64);
    }
    if (lane == 0) { dsum[w] = den0; dsum[4 + w] = den1; }
    __syncthreads();                      // publishes ssrc/sw0/sw1/dsum
    den0 = dsum[0] + dsum[1] + dsum[2] + dsum[3];
    den1 = dsum[4] + dsum[5] + dsum[6] + dsum[7];

    float a0x = 0.f, a0y = 0.f, a1x = 0.f, a1y = 0.f;
    int j = w;
    for (; j + 4 < cn; j += 8) {          // 2 edges in flight per wave
        int s0 = ssrc[j], s1 = ssrc[j + 4];
        uint2 q0 = h[(size_t)s0 * 64 + lane];
        uint2 q1 = h[(size_t)s1 * 64 + lane];
        float wa0 = sw0[j],     wb0 = sw1[j];
        float wa1 = sw0[j + 4], wb1 = sw1[j + 4];
        a0x += wa0 * bflo(q0.x); a0y += wa0 * bfhi(q0.x);
        a1x += wb0 * bflo(q0.y); a1y += wb0 * bfhi(q0.y);
        a0x += wa1 * bflo(q1.x); a0y += wa1 * bfhi(q1.x);
        a1x += wb1 * bflo(q1.y); a1y += wb1 * bfhi(q1.y);
    }
    if (j < cn) {
        int s0 = ssrc[j];
        uint2 q0 = h[(size_t)s0 * 64 + lane];
        float wa0 = sw0[j], wb0 = sw1[j];
        a0x += wa0 * bflo(q0.x); a0y += wa0 * bfhi(q0.x);
        a1x += wb0 * bflo(q0.y); a1y += wb0 * bfhi(q0.y);
    }
    if (w) part[(w - 1) * 64 + lane] = (float4){a0x, a0y, a1x, a1y};
    __syncthreads();
    if (w == 0) {
        #pragma unroll
        for (int k = 0; k < 3; ++k) {
            float4 p = part[k * 64 + lane];
            a0x += p.x; a0y += p.y; a1x += p.z; a1y += p.w;
        }
        float r0 = 1.f / den0, r1 = 1.f / den1;
        float2 bv = *(const float2*)&bias[lane * 2];
        float2 o0 = { a0x * r0 + bv.x, a0y * r0 + bv.y };
        float2 o1 = { a1x * r1 + bv.x, a1y * r1 + bv.y };
        *(float2*)&out[(size_t)n * 128 + lane * 2]        = o0;
        *(float2*)&out[((size_t)NN + n) * 128 + lane * 2] = o1;
    }
}

// ---------------------------------------------------------------------------
extern "C" void kernel_launch(void* const* d_in, const int* in_sizes, int n_in,
                              void* d_out, int out_size, void* d_ws, size_t ws_size,
                              hipStream_t stream)
{
    const float* x       = (const float*)d_in[0];
    const int*   ei      = (const int*)d_in[1];
    const float* W       = (const float*)d_in[2];
    const float* att_src = (const float*)d_in[3];
    const float* att_dst = (const float*)d_in[4];
    const float* bias    = (const float*)d_in[5];
    float* out = (float*)d_out;

    char* ws = (char*)d_ws;
    unsigned* hbu  = (unsigned*)(ws);              // 10,240,000 B (interleaved h)
    float*    as2  = (float*)(ws + 10240000);      //    160,000 B (float2[NN])
    float*    ad2  = (float*)(ws + 10400000);      //    160,000 B (float2[NN])
    int*      cnt  = (int*)(ws + 10560000);        //     80,000 B
    ushort*   buck = (ushort*)(ws + 10640000);     //  5,120,000 B (NN*CAP ushort)

    hipMemsetAsync(cnt, 0, NN * sizeof(int), stream);
    fused_kernel<<<GEMM_BLOCKS + SCAT_BLOCKS, 256, 0, stream>>>(
        x, W, att_src, att_dst, ei, hbu, as2, ad2, cnt, buck);
    gather_kernel<<<NN, 256, 0, stream>>>((const uint2*)hbu, cnt, buck,
                                          (const float2*)as2, (const float2*)ad2,
                                          bias, out);
}

// Round 10
// 92.377 us; speedup vs baseline: 1.1766x; 1.1766x over previous
//
#include <hip/hip_runtime.h>
#include <hip/hip_bf16.h>
#include <math.h>

#define BB    2
#define NN    20000
#define FF    128
#define EE    640000
#define EP    (EE + NN)      // edges + self loops = 660000
#define CAP   128            // bucket capacity per node (Poisson(33): P(>=128)~1e-43)
#define SLOPE 0.2f

typedef __attribute__((ext_vector_type(8))) short bf16x8;
typedef __attribute__((ext_vector_type(4))) float f32x4;

static __device__ __forceinline__ ushort f2bf(float f) {
    unsigned u = __float_as_uint(f);
    u += 0x7fffu + ((u >> 16) & 1u);     // round-to-nearest-even
    return (ushort)(u >> 16);
}
static __device__ __forceinline__ float bf2f(unsigned hw) {
    return __uint_as_float(hw << 16);
}
static __device__ __forceinline__ float bflo(unsigned q) {
    return __uint_as_float(q << 16);
}
static __device__ __forceinline__ float bfhi(unsigned q) {
    return __uint_as_float(q & 0xffff0000u);
}

// ---------------------------------------------------------------------------
// MFMA GEMM: h = bf16(x) @ bf16(W)^T, f32 accumulate. Zeroes cnt[].
// h stored batch-interleaved: hbu[n*128 + pair*2 + b] = bf16x2(h[b][n][2p..2p+1])
// Block: 256 thr (4 waves), tile 64 rows x 128 cols, K=128.
// LDS tiles XOR-swizzled (byte ^= (row&7)<<4) -> conflict-free ds_read_b128.
// ---------------------------------------------------------------------------
__global__ __launch_bounds__(256) void gemm_att_kernel(
    const float* __restrict__ x, const float* __restrict__ W,
    const float* __restrict__ att_src, const float* __restrict__ att_dst,
    unsigned* __restrict__ hbu, float* __restrict__ as2, float* __restrict__ ad2,
    int* __restrict__ cnt)
{
    __shared__ ushort XL[64 * 128];    // 16 KB swizzled bf16 x-tile
    __shared__ ushort WL[128 * 128];   // 32 KB swizzled bf16 W (row c, col k)
    const int tid = threadIdx.x;
    const int r0 = blockIdx.x * 64;

    // zero bucket counters (gemm completes before scatter launches)
    if (blockIdx.x < 79) {
        int i = blockIdx.x * 256 + tid;
        if (i < NN) cnt[i] = 0;
    }

    // stage x tile: 64 rows x 128 f32 = 2048 float4
    {
        const float4* xg = (const float4*)(x + (size_t)r0 * 128);
        #pragma unroll
        for (int i = 0; i < 8; ++i) {
            int idx = tid + i * 256;          // float4 idx; 32 per row
            int r = idx >> 5, k = (idx & 31) * 4;
            float4 v = xg[idx];
            ushort4 p = { f2bf(v.x), f2bf(v.y), f2bf(v.z), f2bf(v.w) };
            unsigned byte = ((unsigned)r << 8) + ((unsigned)k << 1);
            byte ^= (unsigned)(r & 7) << 4;
            *(ushort4*)((char*)XL + byte) = p;
        }
    }
    // stage W: 128x128 f32 = 4096 float4
    {
        const float4* wg = (const float4*)W;
        #pragma unroll
        for (int i = 0; i < 16; ++i) {
            int idx = tid + i * 256;
            int c = idx >> 5, k = (idx & 31) * 4;
            float4 v = wg[idx];
            ushort4 p = { f2bf(v.x), f2bf(v.y), f2bf(v.z), f2bf(v.w) };
            unsigned byte = ((unsigned)c << 8) + ((unsigned)k << 1);
            byte ^= (unsigned)(c & 7) << 4;
            *(ushort4*)((char*)WL + byte) = p;
        }
    }
    __syncthreads();

    const int wid = tid >> 6, lane = tid & 63;
    const int l15 = lane & 15, lg = lane >> 4;
    f32x4 acc[8];
    #pragma unroll
    for (int i = 0; i < 8; ++i) acc[i] = (f32x4){0.f, 0.f, 0.f, 0.f};

    const int arow = wid * 16 + l15;
    #pragma unroll
    for (int kt = 0; kt < 4; ++kt) {
        unsigned abyte = ((unsigned)arow << 8) + (unsigned)(kt * 64 + lg * 16);
        abyte ^= (unsigned)(arow & 7) << 4;
        bf16x8 af = *(const bf16x8*)((const char*)XL + abyte);
        #pragma unroll
        for (int ct = 0; ct < 8; ++ct) {
            int c = ct * 16 + l15;
            unsigned bbyte = ((unsigned)c << 8) + (unsigned)(kt * 64 + lg * 16);
            bbyte ^= (unsigned)(c & 7) << 4;
            bf16x8 bfr = *(const bf16x8*)((const char*)WL + bbyte);
            acc[ct] = __builtin_amdgcn_mfma_f32_16x16x32_bf16(af, bfr, acc[ct], 0, 0, 0);
        }
    }

    // a_src/a_dst from f32 accumulators: row = wid*16 + lg*4 + reg, col = ct*16+l15
    float ps0=0,ps1=0,ps2=0,ps3=0, pd0=0,pd1=0,pd2=0,pd3=0;
    #pragma unroll
    for (int ct = 0; ct < 8; ++ct) {
        int c = ct * 16 + l15;
        float as_ = att_src[c], ad_ = att_dst[c];
        ps0 += acc[ct][0]*as_; pd0 += acc[ct][0]*ad_;
        ps1 += acc[ct][1]*as_; pd1 += acc[ct][1]*ad_;
        ps2 += acc[ct][2]*as_; pd2 += acc[ct][2]*ad_;
        ps3 += acc[ct][3]*as_; pd3 += acc[ct][3]*ad_;
    }
    #pragma unroll
    for (int o = 1; o < 16; o <<= 1) {
        ps0 += __shfl_xor(ps0, o, 64); pd0 += __shfl_xor(pd0, o, 64);
        ps1 += __shfl_xor(ps1, o, 64); pd1 += __shfl_xor(pd1, o, 64);
        ps2 += __shfl_xor(ps2, o, 64); pd2 += __shfl_xor(pd2, o, 64);
        ps3 += __shfl_xor(ps3, o, 64); pd3 += __shfl_xor(pd3, o, 64);
    }
    if (l15 == 0) {
        int rb = r0 + wid * 16 + lg * 4;     // multiple of 4; quads never cross NN
        #pragma unroll
        for (int q = 0; q < 4; ++q) {
            int r = rb + q;
            int b = (r >= NN);
            int n = r - b * NN;
            float ps = q==0?ps0 : q==1?ps1 : q==2?ps2 : ps3;
            float pd = q==0?pd0 : q==1?pd1 : q==2?pd2 : pd3;
            as2[n * 2 + b] = ps;             // batch-packed float2 halves
            ad2[n * 2 + b] = pd;
        }
    }

    // h epilogue: acc -> LDS bf16 (linear) -> batch-interleaved global write
    __syncthreads();
    ushort* hl = (ushort*)WL;          // reuse 16 KB of WL
    {
        int rb = wid * 16 + lg * 4;
        #pragma unroll
        for (int ct = 0; ct < 8; ++ct) {
            int c = ct * 16 + l15;
            hl[(rb+0) * 128 + c] = f2bf(acc[ct][0]);
            hl[(rb+1) * 128 + c] = f2bf(acc[ct][1]);
            hl[(rb+2) * 128 + c] = f2bf(acc[ct][2]);
            hl[(rb+3) * 128 + c] = f2bf(acc[ct][3]);
        }
    }
    __syncthreads();
    {
        const unsigned* hs = (const unsigned*)hl;   // 64 rows x 64 pairs
        #pragma unroll
        for (int i = 0; i < 16; ++i) {
            int idx = tid + i * 256;       // 0..4095
            int row = idx >> 6, p = idx & 63;
            int r = r0 + row;
            int b = (r >= NN);
            int n = r - b * NN;
            hbu[(size_t)n * 128 + p * 2 + b] = hs[row * 64 + p];
        }
    }
}

// ---------------------------------------------------------------------------
// Scatter: per edge, compute both batches' exp-weights (random a-lookups are
// latency-hidden by 660k parallel threads) and write one 8-B record:
// {src:u16 | w0:bf16<<16, w1:bf16}. Minimal resources -> full occupancy.
// ---------------------------------------------------------------------------
__global__ __launch_bounds__(256) void scatter_kernel(
    const int* __restrict__ ei,
    const float2* __restrict__ as2, const float2* __restrict__ ad2,
    int* __restrict__ cnt, uint2* __restrict__ buck)
{
    int e = blockIdx.x * blockDim.x + threadIdx.x;
    if (e >= EP) return;
    int s, d;
    if (e < EE) {
        s = ei[e]; d = ei[EE + e];
        if ((unsigned)s >= NN || (unsigned)d >= NN) return;
    } else {
        s = d = e - EE;
    }
    float2 av = as2[s];
    float2 dv = ad2[d];
    float l0 = av.x + dv.x; l0 = l0 > 0.f ? l0 : SLOPE * l0;
    float l1 = av.y + dv.y; l1 = l1 > 0.f ? l1 : SLOPE * l1;
    unsigned w0 = f2bf(__expf(l0));
    unsigned w1 = f2bf(__expf(l1));
    int slot = atomicAdd(&cnt[d], 1);
    if (slot < CAP) {
        uint2 rec = { (unsigned)s | (w0 << 16), w1 };
        buck[(size_t)d * CAP + slot] = rec;
    }
}

// ---------------------------------------------------------------------------
// Gather: ONE WAVE per node (4 nodes per 256-thr block). No __syncthreads.
// Stage: 2 coalesced uint2 record loads; den via wave shuffle.
// Inner loop: unroll x4 -> 4 h-loads (512 B each) in flight per wave.
// ---------------------------------------------------------------------------
__global__ __launch_bounds__(256) void gather_kernel(
    const uint2* __restrict__ h,             // [N][64] uint2 {b0 pair, b1 pair}
    const int* __restrict__ cnt, const uint2* __restrict__ buck,
    const float* __restrict__ bias, float* __restrict__ out)
{
    const int tid = threadIdx.x;
    const int wid = tid >> 6, lane = tid & 63;
    const int n = blockIdx.x * 4 + wid;

    __shared__ int    ssrc[4][128];
    __shared__ float2 swp[4][128];

    const int cn = min(cnt[n], CAP);

    float den0 = 0.f, den1 = 0.f;
    #pragma unroll
    for (int r = 0; r < 2; ++r) {
        int j = r * 64 + lane;
        if (j < cn) {
            uint2 rec = buck[(size_t)n * CAP + j];
            float w0 = bf2f(rec.x >> 16);
            float w1 = bf2f(rec.y & 0xffffu);
            ssrc[wid][j] = (int)(rec.x & 0xffffu);
            swp[wid][j] = (float2){w0, w1};
            den0 += w0; den1 += w1;
        }
    }
    #pragma unroll
    for (int o = 32; o > 0; o >>= 1) {
        den0 += __shfl_xor(den0, o, 64);
        den1 += __shfl_xor(den1, o, 64);
    }

    float a0x = 0.f, a0y = 0.f, a1x = 0.f, a1y = 0.f;
    int j = 0;
    for (; j + 3 < cn; j += 4) {
        int s0 = ssrc[wid][j],     s1 = ssrc[wid][j + 1];
        int s2 = ssrc[wid][j + 2], s3 = ssrc[wid][j + 3];
        uint2 q0 = h[(size_t)s0 * 64 + lane];
        uint2 q1 = h[(size_t)s1 * 64 + lane];
        uint2 q2 = h[(size_t)s2 * 64 + lane];
        uint2 q3 = h[(size_t)s3 * 64 + lane];
        float2 w0 = swp[wid][j],     w1 = swp[wid][j + 1];
        float2 w2 = swp[wid][j + 2], w3 = swp[wid][j + 3];
        a0x += w0.x * bflo(q0.x); a0y += w0.x * bfhi(q0.x);
        a1x += w0.y * bflo(q0.y); a1y += w0.y * bfhi(q0.y);
        a0x += w1.x * bflo(q1.x); a0y += w1.x * bfhi(q1.x);
        a1x += w1.y * bflo(q1.y); a1y += w1.y * bfhi(q1.y);
        a0x += w2.x * bflo(q2.x); a0y += w2.x * bfhi(q2.x);
        a1x += w2.y * bflo(q2.y); a1y += w2.y * bfhi(q2.y);
        a0x += w3.x * bflo(q3.x); a0y += w3.x * bfhi(q3.x);
        a1x += w3.y * bflo(q3.y); a1y += w3.y * bfhi(q3.y);
    }
    for (; j < cn; ++j) {
        int s0 = ssrc[wid][j];
        uint2 q0 = h[(size_t)s0 * 64 + lane];
        float2 w0 = swp[wid][j];
        a0x += w0.x * bflo(q0.x); a0y += w0.x * bfhi(q0.x);
        a1x += w0.y * bflo(q0.y); a1y += w0.y * bfhi(q0.y);
    }

    float r0 = 1.f / den0, r1 = 1.f / den1;
    float2 bv = *(const float2*)&bias[lane * 2];
    float2 o0 = { a0x * r0 + bv.x, a0y * r0 + bv.y };
    float2 o1 = { a1x * r1 + bv.x, a1y * r1 + bv.y };
    *(float2*)&out[(size_t)n * 128 + lane * 2]        = o0;
    *(float2*)&out[((size_t)NN + n) * 128 + lane * 2] = o1;
}

// ---------------------------------------------------------------------------
extern "C" void kernel_launch(void* const* d_in, const int* in_sizes, int n_in,
                              void* d_out, int out_size, void* d_ws, size_t ws_size,
                              hipStream_t stream)
{
    const float* x       = (const float*)d_in[0];
    const int*   ei      = (const int*)d_in[1];
    const float* W       = (const float*)d_in[2];
    const float* att_src = (const float*)d_in[3];
    const float* att_dst = (const float*)d_in[4];
    const float* bias    = (const float*)d_in[5];
    float* out = (float*)d_out;

    char* ws = (char*)d_ws;
    unsigned* hbu  = (unsigned*)(ws);              // 10,240,000 B (interleaved h)
    float*    as2  = (float*)(ws + 10240000);      //    160,000 B (float2[NN])
    float*    ad2  = (float*)(ws + 10400000);      //    160,000 B (float2[NN])
    int*      cnt  = (int*)(ws + 10560000);        //     80,000 B
    uint2*    buck = (uint2*)(ws + 10640000);      // 20,480,000 B (NN*CAP uint2)

    gemm_att_kernel<<<(BB * NN) / 64, 256, 0, stream>>>(x, W, att_src, att_dst,
                                                        hbu, as2, ad2, cnt);
    scatter_kernel<<<(EP + 255) / 256, 256, 0, stream>>>(
        ei, (const float2*)as2, (const float2*)ad2, cnt, buck);
    gather_kernel<<<NN / 4, 256, 0, stream>>>((const uint2*)hbu, cnt, buck,
                                              bias, out);
}